// Round 5
// baseline (157.470 us; speedup 1.0000x reference)
//
#include <hip/hip_runtime.h>
#include <hip/hip_bf16.h>

// EdgeDecoder: out[e] = W2 @ relu(W1 @ [z[src]; z[dst]] + b1) + b2
// Restructure: W1 = [W1a | W1b] over the concat ->
//   U[n] = W1a @ z[n], V[n] = W1b @ z[n]  (3.28 GFLOP once, via MFMA)
//   out[e] = dot(relu(U[src]+V[dst]+b1), W2) + b2
// Phase 1 computes C'[o, node] = W1t^T . z^T with mfma_f32_16x16x32_bf16 so
// the C/D layout (col=lane&15 -> node, row=quad*4+reg -> output) gives each
// lane 4 consecutive outputs of one node: one packed 8B store, no transpose.
// R5: phase 1 was latency-starved (42.8us, all pipes <6% busy, 12 waves/CU,
// 4 serial load rounds). Now 32 nodes x 64 outputs per wave (6252 waves) and
// ALL 32 load ops issued in dependence-free batches before any MFMA -> one
// memory round-trip per wave instead of four.
// U/V stored bf16 in d_ws (25.6 MB) to halve phase-2 gathers.

#define N_NODES 50000
#define N_EDGES 640000
#define H 128

using bf16 = __hip_bfloat16;
typedef __attribute__((ext_vector_type(8))) short short8;  // 8 bf16, 4 VGPRs
typedef __attribute__((ext_vector_type(4))) float f32x4;   // MFMA acc

static __device__ __forceinline__ short bfbits(float x) {
  __hip_bfloat16 h = __float2bfloat16(x);
  return *reinterpret_cast<short*>(&h);
}

static __device__ __forceinline__ short8 pack8(float4 a, float4 b) {
  short8 r;
  r[0] = bfbits(a.x); r[1] = bfbits(a.y); r[2] = bfbits(a.z); r[3] = bfbits(a.w);
  r[4] = bfbits(b.x); r[5] = bfbits(b.y); r[6] = bfbits(b.z); r[7] = bfbits(b.w);
  return r;
}

// Phase 1: block = 4 waves = one 32-node tile; wave s owns outputs
// [s*64, s*64+64). A-frag (W1t^T): lane holds o = s*64+t*16+(l&15),
// k = quad*8 + q*32 ..+8. B-frag (z^T): lane holds node, same k split.
// K=128 -> 4 MFMA steps per (node-subtile, o-tile).
__global__ __launch_bounds__(256) void precompute_uv(
    const float* __restrict__ z, const float* __restrict__ W1,
    bf16* __restrict__ U, bf16* __restrict__ V) {
  const int lane = threadIdx.x & 63;
  const int s = threadIdx.x >> 6;  // o-split 0..3
  const int l15 = lane & 15, quad = lane >> 4;
  const int nodebase = blockIdx.x * 32;

  // Batch 1: 16 W loads (L2-resident after first touch), packed to bf16.
  short8 wf[4][4];  // [o-tile][k-step]
#pragma unroll
  for (int t = 0; t < 4; ++t) {
    const int o = s * 64 + t * 16 + l15;
    const float* wp = W1 + (size_t)(o & (H - 1)) * (2 * H) + (o >> 7) * H + quad * 8;
#pragma unroll
    for (int q = 0; q < 4; ++q) {
      const float4* p = reinterpret_cast<const float4*>(wp + q * 32);
      wf[t][q] = pack8(p[0], p[1]);
    }
  }

  // Batch 2: 16 z loads for both 16-node subtiles (independent of batch 1).
  int node[2];
  short8 zf[2][4];
#pragma unroll
  for (int m = 0; m < 2; ++m) {
    node[m] = nodebase + m * 16 + l15;
    const int nodeC = node[m] < N_NODES ? node[m] : N_NODES - 1;  // clamp loads
    const float* zp = z + (size_t)nodeC * H + quad * 8;
#pragma unroll
    for (int q = 0; q < 4; ++q) {
      const float4* p = reinterpret_cast<const float4*>(zp + q * 32);
      zf[m][q] = pack8(p[0], p[1]);
    }
  }

  // Compute: 32 back-to-back MFMAs from registers.
  f32x4 acc[2][4] = {};
#pragma unroll
  for (int m = 0; m < 2; ++m)
#pragma unroll
    for (int t = 0; t < 4; ++t)
#pragma unroll
      for (int q = 0; q < 4; ++q)
        acc[m][t] =
            __builtin_amdgcn_mfma_f32_16x16x32_bf16(wf[t][q], zf[m][q], acc[m][t], 0, 0, 0);

  // Epilogue: lane holds 4 consecutive outputs (o = s*64+t*16+quad*4) of node[m].
#pragma unroll
  for (int m = 0; m < 2; ++m) {
    if (node[m] < N_NODES) {
#pragma unroll
      for (int t = 0; t < 4; ++t) {
        const int o = s * 64 + t * 16 + quad * 4;
        bf16* base = (o < H) ? U : V;
        ushort4 st;
        st.x = (unsigned short)bfbits(acc[m][t][0]);
        st.y = (unsigned short)bfbits(acc[m][t][1]);
        st.z = (unsigned short)bfbits(acc[m][t][2]);
        st.w = (unsigned short)bfbits(acc[m][t][3]);
        *reinterpret_cast<ushort4*>(base + (size_t)node[m] * H + (o & (H - 1))) = st;
      }
    }
  }
}

static __device__ __forceinline__ void acc2(unsigned u, unsigned v,
                                            float b1lo, float b1hi,
                                            float w2lo, float w2hi, float& sum) {
  const float ulo = __uint_as_float(u << 16);
  const float uhi = __uint_as_float(u & 0xffff0000u);
  const float vlo = __uint_as_float(v << 16);
  const float vhi = __uint_as_float(v & 0xffff0000u);
  float h0 = ulo + vlo + b1lo; h0 = fmaxf(h0, 0.f);
  float h1 = uhi + vhi + b1hi; h1 = fmaxf(h1, 0.f);
  sum = fmaf(h0, w2lo, sum);
  sum = fmaf(h1, w2hi, sum);
}

// Phase 2: one wave per 64-edge chunk. 8-lane group per edge; lane owns 16
// hidden elems = 2x16B U loads + 2x16B V loads. Gathers batched 4 edges deep
// (16 outstanding uint4 loads/lane) to hide L2/L3 gather latency.
__global__ __launch_bounds__(256, 4) void edge_decode(
    const int* __restrict__ eidx, const bf16* __restrict__ Ub,
    const bf16* __restrict__ Vb, const float* __restrict__ bias1,
    const float* __restrict__ W2, const float* __restrict__ bias2,
    float* __restrict__ out) {
  const int lane = threadIdx.x & 63;
  const int w = blockIdx.x * 4 + (int)(threadIdx.x >> 6);
  const int chunk = w * 64;
  const int e8 = lane & 7;

  float b1r[16], w2r[16];
  const float4* bp = reinterpret_cast<const float4*>(bias1 + e8 * 16);
  const float4* wp = reinterpret_cast<const float4*>(W2 + e8 * 16);
#pragma unroll
  for (int q = 0; q < 4; ++q) {
    const float4 b = bp[q], wv = wp[q];
    b1r[q * 4 + 0] = b.x; b1r[q * 4 + 1] = b.y; b1r[q * 4 + 2] = b.z; b1r[q * 4 + 3] = b.w;
    w2r[q * 4 + 0] = wv.x; w2r[q * 4 + 1] = wv.y; w2r[q * 4 + 2] = wv.z; w2r[q * 4 + 3] = wv.w;
  }
  const float b2 = bias2[0];

  const int src = eidx[chunk + lane];
  const int dst = eidx[N_EDGES + chunk + lane];
  const uint4* U4 = reinterpret_cast<const uint4*>(Ub);  // row = 16 uint4
  const uint4* V4 = reinterpret_cast<const uint4*>(Vb);

  float res = 0.f;
#pragma unroll
  for (int half = 0; half < 2; ++half) {
    uint4 ua[4], ub[4], va[4], vb[4];
    // Issue all 16 gather loads for 4 edges before any compute.
#pragma unroll
    for (int j = 0; j < 4; ++j) {
      const int i = half * 4 + j;
      const int sl = (lane & 56) + i;
      const int s_i = __shfl(src, sl);
      const int d_i = __shfl(dst, sl);
      const uint4* up = U4 + (size_t)s_i * 16 + e8 * 2;
      const uint4* vp = V4 + (size_t)d_i * 16 + e8 * 2;
      ua[j] = up[0]; ub[j] = up[1];
      va[j] = vp[0]; vb[j] = vp[1];
    }
#pragma unroll
    for (int j = 0; j < 4; ++j) {
      const int i = half * 4 + j;
      float sum = 0.f;
      acc2(ua[j].x, va[j].x, b1r[0],  b1r[1],  w2r[0],  w2r[1],  sum);
      acc2(ua[j].y, va[j].y, b1r[2],  b1r[3],  w2r[2],  w2r[3],  sum);
      acc2(ua[j].z, va[j].z, b1r[4],  b1r[5],  w2r[4],  w2r[5],  sum);
      acc2(ua[j].w, va[j].w, b1r[6],  b1r[7],  w2r[6],  w2r[7],  sum);
      acc2(ub[j].x, vb[j].x, b1r[8],  b1r[9],  w2r[8],  w2r[9],  sum);
      acc2(ub[j].y, vb[j].y, b1r[10], b1r[11], w2r[10], w2r[11], sum);
      acc2(ub[j].z, vb[j].z, b1r[12], b1r[13], w2r[12], w2r[13], sum);
      acc2(ub[j].w, vb[j].w, b1r[14], b1r[15], w2r[14], w2r[15], sum);
      sum += __shfl_xor(sum, 1);
      sum += __shfl_xor(sum, 2);
      sum += __shfl_xor(sum, 4);
      if (e8 == i) res = sum + b2;
    }
  }
  out[chunk + lane] = res;  // coalesced 4 B/lane
}

extern "C" void kernel_launch(void* const* d_in, const int* in_sizes, int n_in,
                              void* d_out, int out_size, void* d_ws, size_t ws_size,
                              hipStream_t stream) {
  const float* z     = (const float*)d_in[0];
  const float* W1    = (const float*)d_in[1];
  const float* bias1 = (const float*)d_in[2];
  const float* W2    = (const float*)d_in[3];
  const float* bias2 = (const float*)d_in[4];
  const int*   eidx  = (const int*)d_in[5];
  float* out = (float*)d_out;

  bf16* U = (bf16*)d_ws;              // [N_NODES, H] bf16
  bf16* V = U + (size_t)N_NODES * H;  // [N_NODES, H] bf16 (25.6 MB total)

  // Phase 1: 1563 blocks x 4 waves; block = 32-node tile, wave = 64-output split.
  hipLaunchKernelGGL(precompute_uv, dim3((N_NODES + 31) / 32), dim3(256), 0, stream,
                     z, W1, U, V);
  // Phase 2: 10000 waves, one 64-edge chunk each.
  hipLaunchKernelGGL(edge_decode, dim3(N_EDGES / 64 / 4), dim3(256), 0, stream,
                     eidx, U, V, bias1, W2, bias2, out);
}

// Round 6
// 143.139 us; speedup vs baseline: 1.1001x; 1.1001x over previous
//
#include <hip/hip_runtime.h>
#include <hip/hip_bf16.h>

// EdgeDecoder: out[e] = W2 @ relu(W1 @ [z[src]; z[dst]] + b1) + b2
// Restructure: W1 = [W1a | W1b] over the concat ->
//   U[n] = W1a @ z[n], V[n] = W1b @ z[n]  (3.28 GFLOP once, via MFMA)
//   out[e] = dot(relu(U[src]+V[dst]+b1), W2) + b2
//
// R6: R5 post-mortem showed phase 1 was a serial load->cvt->reuse chain
// (VGPR 84: the compiler couldn't keep batched fp32 loads in flight; ~48
// serialized ~375cy round-trips/wave = 18k cyc serial, occupancy 21%).
// Fix: (1) to_bf16 streaming pre-pass converts z and W1 to bf16 once
// (BW-bound, latency hidden by 200k waves); (2) precompute_uv loads 16B
// bf16 DIRECTLY into MFMA frag registers - no dependent cvt, all 24 loads
// in flight; (3) epilogue transposes via LDS so U/V stores are contiguous
// 1024B/wave dwordx4 instead of 8B scatter at 256B stride.

#define N_NODES 50000
#define N_EDGES 640000
#define H 128

using bf16 = __hip_bfloat16;
typedef __attribute__((ext_vector_type(8))) short short8;  // 8 bf16, 4 VGPRs
typedef __attribute__((ext_vector_type(4))) float f32x4;   // MFMA acc

static __device__ __forceinline__ short bfbits(float x) {
  __hip_bfloat16 h = __float2bfloat16(x);
  return *reinterpret_cast<short*>(&h);
}

static __device__ __forceinline__ short8 pack8(float4 a, float4 b) {
  short8 r;
  r[0] = bfbits(a.x); r[1] = bfbits(a.y); r[2] = bfbits(a.z); r[3] = bfbits(a.w);
  r[4] = bfbits(b.x); r[5] = bfbits(b.y); r[6] = bfbits(b.z); r[7] = bfbits(b.w);
  return r;
}

#define ZUNITS (N_NODES * H / 8)  // 800000 8-elem units
#define WUNITS (2 * H * H / 8)    // 4096

// Streaming fp32->bf16 convert. zb[n][k] = z[n][k]; Wb[o][k] = row o of the
// A-operand matrix: o<128 -> W1[o][k], o>=128 -> W1[o-128][128+k].
__global__ __launch_bounds__(256) void to_bf16(
    const float* __restrict__ z, const float* __restrict__ W1,
    bf16* __restrict__ zb, bf16* __restrict__ Wb) {
  const int u = blockIdx.x * 256 + threadIdx.x;
  const float4* src;
  bf16* dst;
  if (u < ZUNITS) {
    src = reinterpret_cast<const float4*>(z) + (size_t)u * 2;
    dst = zb + (size_t)u * 8;
  } else if (u < ZUNITS + WUNITS) {
    const int w = u - ZUNITS;
    const int o = w >> 4;          // 16 units per 128-wide row
    const int k8 = (w & 15) * 8;
    src = reinterpret_cast<const float4*>(W1 + (size_t)(o & (H - 1)) * (2 * H) +
                                          (o >> 7) * H + k8);
    dst = Wb + (size_t)o * H + k8;
  } else {
    return;
  }
  *reinterpret_cast<short8*>(dst) = pack8(src[0], src[1]);
}

// Phase 1: block = 4 waves = one 32-node tile; wave s owns outputs
// [s*64, s*64+64). All frag loads are direct 16B bf16 -> no cvt chain.
// K=128 -> 4 MFMA steps per (node-subtile, o-tile).
__global__ __launch_bounds__(256) void precompute_uv(
    const bf16* __restrict__ zb, const bf16* __restrict__ Wb,
    bf16* __restrict__ U, bf16* __restrict__ V) {
  __shared__ bf16 tile[32][2 * H + 8];  // +8 pad: LDS bank spread
  const int lane = threadIdx.x & 63;
  const int s = threadIdx.x >> 6;  // o-split 0..3
  const int l15 = lane & 15, quad = lane >> 4;
  const int nodebase = blockIdx.x * 32;

  // 16 W-frag loads + 8 z-frag loads, all independent, direct to registers.
  short8 wf[4][4];  // [o-tile][k-step]
#pragma unroll
  for (int t = 0; t < 4; ++t) {
    const int o = s * 64 + t * 16 + l15;
    const bf16* wp = Wb + (size_t)o * H + quad * 8;
#pragma unroll
    for (int q = 0; q < 4; ++q)
      wf[t][q] = *reinterpret_cast<const short8*>(wp + q * 32);
  }
  int node[2];
  short8 zf[2][4];
#pragma unroll
  for (int m = 0; m < 2; ++m) {
    node[m] = nodebase + m * 16 + l15;
    const int nodeC = node[m] < N_NODES ? node[m] : N_NODES - 1;  // clamp loads
    const bf16* zp = zb + (size_t)nodeC * H + quad * 8;
#pragma unroll
    for (int q = 0; q < 4; ++q)
      zf[m][q] = *reinterpret_cast<const short8*>(zp + q * 32);
  }

  // 32 back-to-back MFMAs from registers.
  f32x4 acc[2][4] = {};
#pragma unroll
  for (int m = 0; m < 2; ++m)
#pragma unroll
    for (int t = 0; t < 4; ++t)
#pragma unroll
      for (int q = 0; q < 4; ++q)
        acc[m][t] =
            __builtin_amdgcn_mfma_f32_16x16x32_bf16(wf[t][q], zf[m][q], acc[m][t], 0, 0, 0);

  // Epilogue 1: acc -> LDS. Lane holds o = s*64+t*16+quad*4 ..+4 of local
  // node nl = m*16+l15 (C/D layout: col=l15 -> node, row=quad*4+reg -> o).
#pragma unroll
  for (int m = 0; m < 2; ++m) {
    const int nl = m * 16 + l15;
#pragma unroll
    for (int t = 0; t < 4; ++t) {
      const int o = s * 64 + t * 16 + quad * 4;
      ushort4 st;
      st.x = (unsigned short)bfbits(acc[m][t][0]);
      st.y = (unsigned short)bfbits(acc[m][t][1]);
      st.z = (unsigned short)bfbits(acc[m][t][2]);
      st.w = (unsigned short)bfbits(acc[m][t][3]);
      *reinterpret_cast<ushort4*>(&tile[nl][o]) = st;
    }
  }
  __syncthreads();

  // Epilogue 2: coalesced stores. Wave s owns local nodes s*8..s*8+8; each
  // store instr covers 4 node-rows x 256B = contiguous 1024B of U (or V).
#pragma unroll
  for (int half = 0; half < 2; ++half) {
    bf16* base = half ? V : U;
#pragma unroll
    for (int it = 0; it < 2; ++it) {
      const int nl = s * 8 + it * 4 + (lane >> 4);
      const int oc = (lane & 15) * 8;
      const short8 v = *reinterpret_cast<const short8*>(&tile[nl][half * H + oc]);
      const int n = nodebase + nl;
      if (n < N_NODES)
        *reinterpret_cast<short8*>(base + (size_t)n * H + oc) = v;
    }
  }
}

static __device__ __forceinline__ void acc2(unsigned u, unsigned v,
                                            float b1lo, float b1hi,
                                            float w2lo, float w2hi, float& sum) {
  const float ulo = __uint_as_float(u << 16);
  const float uhi = __uint_as_float(u & 0xffff0000u);
  const float vlo = __uint_as_float(v << 16);
  const float vhi = __uint_as_float(v & 0xffff0000u);
  float h0 = ulo + vlo + b1lo; h0 = fmaxf(h0, 0.f);
  float h1 = uhi + vhi + b1hi; h1 = fmaxf(h1, 0.f);
  sum = fmaf(h0, w2lo, sum);
  sum = fmaf(h1, w2hi, sum);
}

// Phase 2: one wave per 64-edge chunk. 8-lane group per edge; lane owns 16
// hidden elems = 2x16B U loads + 2x16B V loads. Gathers batched 4 edges deep
// (16 outstanding uint4 loads/lane) to hide L2/L3 gather latency.
__global__ __launch_bounds__(256, 4) void edge_decode(
    const int* __restrict__ eidx, const bf16* __restrict__ Ub,
    const bf16* __restrict__ Vb, const float* __restrict__ bias1,
    const float* __restrict__ W2, const float* __restrict__ bias2,
    float* __restrict__ out) {
  const int lane = threadIdx.x & 63;
  const int w = blockIdx.x * 4 + (int)(threadIdx.x >> 6);
  const int chunk = w * 64;
  const int e8 = lane & 7;

  float b1r[16], w2r[16];
  const float4* bp = reinterpret_cast<const float4*>(bias1 + e8 * 16);
  const float4* wp = reinterpret_cast<const float4*>(W2 + e8 * 16);
#pragma unroll
  for (int q = 0; q < 4; ++q) {
    const float4 b = bp[q], wv = wp[q];
    b1r[q * 4 + 0] = b.x; b1r[q * 4 + 1] = b.y; b1r[q * 4 + 2] = b.z; b1r[q * 4 + 3] = b.w;
    w2r[q * 4 + 0] = wv.x; w2r[q * 4 + 1] = wv.y; w2r[q * 4 + 2] = wv.z; w2r[q * 4 + 3] = wv.w;
  }
  const float b2 = bias2[0];

  const int src = eidx[chunk + lane];
  const int dst = eidx[N_EDGES + chunk + lane];
  const uint4* U4 = reinterpret_cast<const uint4*>(Ub);  // row = 16 uint4
  const uint4* V4 = reinterpret_cast<const uint4*>(Vb);

  float res = 0.f;
#pragma unroll
  for (int half = 0; half < 2; ++half) {
    uint4 ua[4], ub[4], va[4], vb[4];
    // Issue all 16 gather loads for 4 edges before any compute.
#pragma unroll
    for (int j = 0; j < 4; ++j) {
      const int i = half * 4 + j;
      const int sl = (lane & 56) + i;
      const int s_i = __shfl(src, sl);
      const int d_i = __shfl(dst, sl);
      const uint4* up = U4 + (size_t)s_i * 16 + e8 * 2;
      const uint4* vp = V4 + (size_t)d_i * 16 + e8 * 2;
      ua[j] = up[0]; ub[j] = up[1];
      va[j] = vp[0]; vb[j] = vp[1];
    }
#pragma unroll
    for (int j = 0; j < 4; ++j) {
      const int i = half * 4 + j;
      float sum = 0.f;
      acc2(ua[j].x, va[j].x, b1r[0],  b1r[1],  w2r[0],  w2r[1],  sum);
      acc2(ua[j].y, va[j].y, b1r[2],  b1r[3],  w2r[2],  w2r[3],  sum);
      acc2(ua[j].z, va[j].z, b1r[4],  b1r[5],  w2r[4],  w2r[5],  sum);
      acc2(ua[j].w, va[j].w, b1r[6],  b1r[7],  w2r[6],  w2r[7],  sum);
      acc2(ub[j].x, vb[j].x, b1r[8],  b1r[9],  w2r[8],  w2r[9],  sum);
      acc2(ub[j].y, vb[j].y, b1r[10], b1r[11], w2r[10], w2r[11], sum);
      acc2(ub[j].z, vb[j].z, b1r[12], b1r[13], w2r[12], w2r[13], sum);
      acc2(ub[j].w, vb[j].w, b1r[14], b1r[15], w2r[14], w2r[15], sum);
      sum += __shfl_xor(sum, 1);
      sum += __shfl_xor(sum, 2);
      sum += __shfl_xor(sum, 4);
      if (e8 == i) res = sum + b2;
    }
  }
  out[chunk + lane] = res;  // coalesced 4 B/lane
}

extern "C" void kernel_launch(void* const* d_in, const int* in_sizes, int n_in,
                              void* d_out, int out_size, void* d_ws, size_t ws_size,
                              hipStream_t stream) {
  const float* z     = (const float*)d_in[0];
  const float* W1    = (const float*)d_in[1];
  const float* bias1 = (const float*)d_in[2];
  const float* W2    = (const float*)d_in[3];
  const float* bias2 = (const float*)d_in[4];
  const int*   eidx  = (const int*)d_in[5];
  float* out = (float*)d_out;

  bf16* U  = (bf16*)d_ws;                     // [N_NODES, H]
  bf16* V  = U + (size_t)N_NODES * H;         // [N_NODES, H]
  bf16* zb = V + (size_t)N_NODES * H;         // [N_NODES, H]
  bf16* Wb = zb + (size_t)N_NODES * H;        // [256, H]  (~38.5 MB total)

  // Pre-pass: 804096 units / 256 = 3141 blocks.
  hipLaunchKernelGGL(to_bf16, dim3((ZUNITS + WUNITS) / 256), dim3(256), 0, stream,
                     z, W1, zb, Wb);
  // Phase 1: 1563 blocks x 4 waves; block = 32-node tile, wave = 64-output split.
  hipLaunchKernelGGL(precompute_uv, dim3((N_NODES + 31) / 32), dim3(256), 0, stream,
                     zb, Wb, U, V);
  // Phase 2: 10000 waves, one 64-edge chunk each.
  hipLaunchKernelGGL(edge_decode, dim3(N_EDGES / 64 / 4), dim3(256), 0, stream,
                     eidx, U, V, bias1, W2, bias2, out);
}

// Round 7
// 137.212 us; speedup vs baseline: 1.1476x; 1.0432x over previous
//
#include <hip/hip_runtime.h>
#include <hip/hip_bf16.h>

// EdgeDecoder: out[e] = W2 @ relu(W1 @ [z[src]; z[dst]] + b1) + b2
// Restructure: W1 = [W1a | W1b] over the concat ->
//   U[n] = W1a @ z[n], V[n] = W1b @ z[n]  (3.28 GFLOP once, via MFMA)
//   out[e] = dot(relu(U[src]+V[dst]+b1), W2) + b2
//
// R7: R5/R6 showed any staging scheme needing ~100 VGPRs of in-flight load
// results gets partially serialized by the register allocator (precompute
// stuck at ~26us, all pipes idle). Fix: global_load_lds DMA (zero dest
// VGPRs) stages fp32 z into LDS; one LDS pass converts to a padded bf16
// tile; frags come from ds_read_b128. Serial chain per wave = one DMA
// round-trip + LDS ops, independent of VGPR budget. zb global round-trip
// deleted; only a tiny W-convert kernel remains.

#define N_NODES 50000
#define N_EDGES 640000
#define H 128

using bf16 = __hip_bfloat16;
typedef __attribute__((ext_vector_type(8))) short short8;  // 8 bf16, 4 VGPRs
typedef __attribute__((ext_vector_type(4))) float f32x4;   // MFMA acc

#define GLD_LDS16(g, l)                                                     \
  __builtin_amdgcn_global_load_lds(                                         \
      (const __attribute__((address_space(1))) void*)(g),                   \
      (__attribute__((address_space(3))) void*)(l), 16, 0, 0)

static __device__ __forceinline__ short bfbits(float x) {
  __hip_bfloat16 h = __float2bfloat16(x);
  return *reinterpret_cast<short*>(&h);
}

static __device__ __forceinline__ short8 pack8(float4 a, float4 b) {
  short8 r;
  r[0] = bfbits(a.x); r[1] = bfbits(a.y); r[2] = bfbits(a.z); r[3] = bfbits(a.w);
  r[4] = bfbits(b.x); r[5] = bfbits(b.y); r[6] = bfbits(b.z); r[7] = bfbits(b.w);
  return r;
}

// Tiny: Wb[o][k] (bf16, A-frag row layout) from fp32 W1. o<128 -> W1[o][k],
// o>=128 -> W1[o-128][128+k]. 4096 units of 8 elems -> 16 blocks.
__global__ __launch_bounds__(256) void w_to_bf16(const float* __restrict__ W1,
                                                 bf16* __restrict__ Wb) {
  const int u = blockIdx.x * 256 + threadIdx.x;
  const int o = u >> 4, k8 = (u & 15) * 8;
  const float4* src = reinterpret_cast<const float4*>(
      W1 + (size_t)(o & (H - 1)) * (2 * H) + (o >> 7) * H + k8);
  *reinterpret_cast<short8*>(Wb + (size_t)o * H + k8) = pack8(src[0], src[1]);
}

#define HP 136  // padded bf16 LDS row stride (272B): breaks 256B-stride conflicts

// Phase 1: block = 4 waves = one 32-node tile; wave s owns outputs
// [s*64, s*64+64). fp32 z staged via global_load_lds DMA (no VGPRs), one
// LDS pass converts to bf16 tile, frags via ds_read_b128, 32 MFMAs, then
// LDS-transposed coalesced epilogue (reusing the fp32 stage buffer).
__global__ __launch_bounds__(256) void precompute_uv(
    const float* __restrict__ z, const bf16* __restrict__ Wb,
    bf16* __restrict__ U, bf16* __restrict__ V) {
  __shared__ float ldsF[32 * H];       // 16 KB: fp32 z stage, later epilogue tile
  __shared__ bf16 ldsH[32 * HP];       // 8.5 KB: padded bf16 z tile
  const int tid = threadIdx.x;
  const int lane = tid & 63;
  const int s = tid >> 6;  // wave id = o-split 0..3
  const int l15 = lane & 15, quad = lane >> 4;
  const int nodebase = blockIdx.x * 32;

  // Stage: wave s DMAs rows [s*8, s*8+8) of the tile; 4 x 1KB contiguous.
  {
    int r0 = nodebase + s * 8;
    if (r0 > N_NODES - 8) r0 = N_NODES - 8;  // tail clamp (stores guarded)
    const float* gsrc = z + (size_t)r0 * H + lane * 4;
    float* ldst = ldsF + s * 8 * H;  // + lane*16B implicit
#pragma unroll
    for (int j = 0; j < 4; ++j) GLD_LDS16(gsrc + j * 256, ldst + j * 256);
  }

  // W-frags from global bf16 (64 KB, L2-hot) — overlaps the DMA.
  short8 wf[4][4];  // [o-tile][k-step]
#pragma unroll
  for (int t = 0; t < 4; ++t) {
    const bf16* wp = Wb + (size_t)(s * 64 + t * 16 + l15) * H + quad * 8;
#pragma unroll
    for (int q = 0; q < 4; ++q)
      wf[t][q] = *reinterpret_cast<const short8*>(wp + q * 32);
  }

  __syncthreads();  // DMA + conversion-input visible

  // Convert: thread handles 16 consecutive fp32 of row (tid>>3).
  {
    const int row = tid >> 3, off = (tid & 7) * 16;
    const float4* fp = reinterpret_cast<const float4*>(ldsF + row * H + off);
    const float4 a = fp[0], b = fp[1], c = fp[2], d = fp[3];
    *reinterpret_cast<short8*>(&ldsH[row * HP + off]) = pack8(a, b);
    *reinterpret_cast<short8*>(&ldsH[row * HP + off + 8]) = pack8(c, d);
  }
  __syncthreads();

  // z-frags from LDS + 32 back-to-back MFMAs.
  short8 zf[2][4];
#pragma unroll
  for (int m = 0; m < 2; ++m)
#pragma unroll
    for (int q = 0; q < 4; ++q)
      zf[m][q] = *reinterpret_cast<const short8*>(
          &ldsH[(m * 16 + l15) * HP + quad * 8 + q * 32]);

  f32x4 acc[2][4] = {};
#pragma unroll
  for (int m = 0; m < 2; ++m)
#pragma unroll
    for (int t = 0; t < 4; ++t)
#pragma unroll
      for (int q = 0; q < 4; ++q)
        acc[m][t] =
            __builtin_amdgcn_mfma_f32_16x16x32_bf16(wf[t][q], zf[m][q], acc[m][t], 0, 0, 0);

  // Epilogue 1: acc -> LDS (reuse ldsF as 32 x 256 bf16, no pad). C/D layout:
  // col=l15 -> node row nl, row=quad*4+reg -> output o.
  bf16* epi = reinterpret_cast<bf16*>(ldsF);
#pragma unroll
  for (int m = 0; m < 2; ++m) {
    const int nl = m * 16 + l15;
#pragma unroll
    for (int t = 0; t < 4; ++t) {
      const int o = s * 64 + t * 16 + quad * 4;
      ushort4 st;
      st.x = (unsigned short)bfbits(acc[m][t][0]);
      st.y = (unsigned short)bfbits(acc[m][t][1]);
      st.z = (unsigned short)bfbits(acc[m][t][2]);
      st.w = (unsigned short)bfbits(acc[m][t][3]);
      *reinterpret_cast<ushort4*>(epi + nl * 256 + o) = st;
    }
  }
  __syncthreads();

  // Epilogue 2: coalesced stores; each instr = 4 node-rows x 256B contiguous.
#pragma unroll
  for (int half = 0; half < 2; ++half) {
    bf16* base = half ? V : U;
#pragma unroll
    for (int it = 0; it < 2; ++it) {
      const int nl = s * 8 + it * 4 + (lane >> 4);
      const int oc = (lane & 15) * 8;
      const short8 v = *reinterpret_cast<const short8*>(epi + nl * 256 + half * H + oc);
      const int n = nodebase + nl;
      if (n < N_NODES)
        *reinterpret_cast<short8*>(base + (size_t)n * H + oc) = v;
    }
  }
}

static __device__ __forceinline__ void acc2(unsigned u, unsigned v,
                                            float b1lo, float b1hi,
                                            float w2lo, float w2hi, float& sum) {
  const float ulo = __uint_as_float(u << 16);
  const float uhi = __uint_as_float(u & 0xffff0000u);
  const float vlo = __uint_as_float(v << 16);
  const float vhi = __uint_as_float(v & 0xffff0000u);
  float h0 = ulo + vlo + b1lo; h0 = fmaxf(h0, 0.f);
  float h1 = uhi + vhi + b1hi; h1 = fmaxf(h1, 0.f);
  sum = fmaf(h0, w2lo, sum);
  sum = fmaf(h1, w2hi, sum);
}

// Phase 2: one wave per 64-edge chunk. 8-lane group per edge; lane owns 16
// hidden elems = 2x16B U loads + 2x16B V loads. Gathers batched 4 edges deep
// (16 outstanding uint4 loads/lane) to hide L2/L3 gather latency.
__global__ __launch_bounds__(256, 4) void edge_decode(
    const int* __restrict__ eidx, const bf16* __restrict__ Ub,
    const bf16* __restrict__ Vb, const float* __restrict__ bias1,
    const float* __restrict__ W2, const float* __restrict__ bias2,
    float* __restrict__ out) {
  const int lane = threadIdx.x & 63;
  const int w = blockIdx.x * 4 + (int)(threadIdx.x >> 6);
  const int chunk = w * 64;
  const int e8 = lane & 7;

  float b1r[16], w2r[16];
  const float4* bp = reinterpret_cast<const float4*>(bias1 + e8 * 16);
  const float4* wp = reinterpret_cast<const float4*>(W2 + e8 * 16);
#pragma unroll
  for (int q = 0; q < 4; ++q) {
    const float4 b = bp[q], wv = wp[q];
    b1r[q * 4 + 0] = b.x; b1r[q * 4 + 1] = b.y; b1r[q * 4 + 2] = b.z; b1r[q * 4 + 3] = b.w;
    w2r[q * 4 + 0] = wv.x; w2r[q * 4 + 1] = wv.y; w2r[q * 4 + 2] = wv.z; w2r[q * 4 + 3] = wv.w;
  }
  const float b2 = bias2[0];

  const int src = eidx[chunk + lane];
  const int dst = eidx[N_EDGES + chunk + lane];
  const uint4* U4 = reinterpret_cast<const uint4*>(Ub);  // row = 16 uint4
  const uint4* V4 = reinterpret_cast<const uint4*>(Vb);

  float res = 0.f;
#pragma unroll
  for (int half = 0; half < 2; ++half) {
    uint4 ua[4], ub[4], va[4], vb[4];
    // Issue all 16 gather loads for 4 edges before any compute.
#pragma unroll
    for (int j = 0; j < 4; ++j) {
      const int i = half * 4 + j;
      const int sl = (lane & 56) + i;
      const int s_i = __shfl(src, sl);
      const int d_i = __shfl(dst, sl);
      const uint4* up = U4 + (size_t)s_i * 16 + e8 * 2;
      const uint4* vp = V4 + (size_t)d_i * 16 + e8 * 2;
      ua[j] = up[0]; ub[j] = up[1];
      va[j] = vp[0]; vb[j] = vp[1];
    }
#pragma unroll
    for (int j = 0; j < 4; ++j) {
      const int i = half * 4 + j;
      float sum = 0.f;
      acc2(ua[j].x, va[j].x, b1r[0],  b1r[1],  w2r[0],  w2r[1],  sum);
      acc2(ua[j].y, va[j].y, b1r[2],  b1r[3],  w2r[2],  w2r[3],  sum);
      acc2(ua[j].z, va[j].z, b1r[4],  b1r[5],  w2r[4],  w2r[5],  sum);
      acc2(ua[j].w, va[j].w, b1r[6],  b1r[7],  w2r[6],  w2r[7],  sum);
      acc2(ub[j].x, vb[j].x, b1r[8],  b1r[9],  w2r[8],  w2r[9],  sum);
      acc2(ub[j].y, vb[j].y, b1r[10], b1r[11], w2r[10], w2r[11], sum);
      acc2(ub[j].z, vb[j].z, b1r[12], b1r[13], w2r[12], w2r[13], sum);
      acc2(ub[j].w, vb[j].w, b1r[14], b1r[15], w2r[14], w2r[15], sum);
      sum += __shfl_xor(sum, 1);
      sum += __shfl_xor(sum, 2);
      sum += __shfl_xor(sum, 4);
      if (e8 == i) res = sum + b2;
    }
  }
  out[chunk + lane] = res;  // coalesced 4 B/lane
}

extern "C" void kernel_launch(void* const* d_in, const int* in_sizes, int n_in,
                              void* d_out, int out_size, void* d_ws, size_t ws_size,
                              hipStream_t stream) {
  const float* z     = (const float*)d_in[0];
  const float* W1    = (const float*)d_in[1];
  const float* bias1 = (const float*)d_in[2];
  const float* W2    = (const float*)d_in[3];
  const float* bias2 = (const float*)d_in[4];
  const int*   eidx  = (const int*)d_in[5];
  float* out = (float*)d_out;

  bf16* U  = (bf16*)d_ws;                // [N_NODES, H]
  bf16* V  = U + (size_t)N_NODES * H;    // [N_NODES, H]
  bf16* Wb = V + (size_t)N_NODES * H;    // [256, H] (64 KB)

  // W convert: 4096 units / 256 = 16 blocks (~1.5 us).
  hipLaunchKernelGGL(w_to_bf16, dim3(16), dim3(256), 0, stream, W1, Wb);
  // Phase 1: 1563 blocks x 4 waves; block = 32-node tile, wave = 64-output split.
  hipLaunchKernelGGL(precompute_uv, dim3((N_NODES + 31) / 32), dim3(256), 0, stream,
                     z, Wb, U, V);
  // Phase 2: 10000 waves, one 64-edge chunk each.
  hipLaunchKernelGGL(edge_decode, dim3(N_EDGES / 64 / 4), dim3(256), 0, stream,
                     eidx, U, V, bias1, W2, bias2, out);
}